// Round 2
// baseline (25328.169 us; speedup 1.0000x reference)
//
#include <hip/hip_runtime.h>
#include <hip/hip_bf16.h>

// SimpleLSTM on MI355X — round 2: contention-free distributed barrier.
//   B=64, S=512, I=512, H=1024, gates = 4H = 4096
// R1 post-mortem: 47 us/step, all pipes idle -> single-cacheline atomic counter
// ping-ponged across 8 XCDs (64 RMWs + 64 pollers per step). R2 replaces it:
//   * per-block arrival flag (128 B stride), release-store only, no RMW
//   * wave-0 polls all 64 flags with ONE lane-parallel acquire load + __all
//   * wh MFMA chain split into two parallel 8-chains (halve dep latency)
//   * fp32 `out` store moved after flag publish (off critical path)

#define BATCH 64
#define SEQ   512
#define ISZ   512
#define HSZ   1024
#define G4    4096

typedef short bf16x8 __attribute__((ext_vector_type(8)));
typedef float f32x4  __attribute__((ext_vector_type(4)));

#define HEX_BYTES (2 * BATCH * HSZ * 2)     // 2 buffers x [64][1024] bf16 = 256 KB
#define FLAG_STRIDE_DW 32                   // 128 B between flags
#define FLAG_BYTES (4 * 64 * FLAG_STRIDE_DW * 4)  // 4 groups x 64 flags = 32 KB

static __device__ __forceinline__ short f2bf(float f) {
    __hip_bfloat16 h = __float2bfloat16(f);
    return *reinterpret_cast<short*>(&h);
}
static __device__ __forceinline__ float sigm(float x) {
    return 1.f / (1.f + __expf(-x));
}
static __device__ __forceinline__ float tanh_fast(float x) {
    x = fminf(15.f, fmaxf(-15.f, x));
    float e = __expf(2.f * x);
    return (e - 1.f) / (e + 1.f);
}

__global__ __launch_bounds__(512) void lstm_persistent(
    const float* __restrict__ x,     // [B][S][I] fp32
    const float* __restrict__ W,     // [I+H][4H] fp32
    const float* __restrict__ bias,  // [4H] fp32
    float* __restrict__ out,         // [B][S][H] outputs, then [B][H] h, [B][H] c
    unsigned short* __restrict__ hex,// [2][B][H] bf16 exchange
    unsigned int* __restrict__ flags)// [4][64] arrival epochs, 128 B stride
{
    const int tid  = threadIdx.x;
    const int bid  = blockIdx.x;
    const int q    = bid & 63;          // CU index within group (owns h cols q*16..+16)
    const int g    = bid >> 6;          // batch group 0..3
    const int w    = tid >> 6;          // wave 0..7
    const int lane = tid & 63;
    const int gb   = w & 3;             // gate block: 0=f 1=i 2=c~ 3=o
    const int kh   = w >> 2;            // K-half split across wave pairs
    const int m16  = lane & 15;
    const int quad = lane >> 4;
    const int batch0 = g * 16;
    const int colbase = gb * 1024 + q * 16;   // gate column base for this wave

    // ---- preload weights into registers as MFMA B-fragments ----
    // B-frag layout (16x16x32 bf16): lane holds B[k = quad*8 + j][n = lane&15]
    bf16x8 wh[16];   // Wh[kh*512 .. +512][colbase..+16], 16 K-chunks of 32
    bf16x8 wx[8];    // Wx[kh*256 .. +256][colbase..+16],  8 K-chunks of 32
    {
        const int n = m16;
        #pragma unroll
        for (int kk = 0; kk < 16; ++kk) {
            #pragma unroll
            for (int j = 0; j < 8; ++j) {
                int k = kh * 512 + kk * 32 + quad * 8 + j;
                wh[kk][j] = f2bf(W[(size_t)(ISZ + k) * G4 + colbase + n]);
            }
        }
        #pragma unroll
        for (int kk = 0; kk < 8; ++kk) {
            #pragma unroll
            for (int j = 0; j < 8; ++j) {
                int k = kh * 256 + kk * 32 + quad * 8 + j;
                wx[kk][j] = f2bf(W[(size_t)k * G4 + colbase + n]);
            }
        }
    }

    // elementwise mapping (tid < 256): m = tid>>4 (batch-in-group), n = tid&15 (col)
    const int em = tid >> 4;
    const int en = tid & 15;
    float bia[4];
    #pragma unroll
    for (int gg = 0; gg < 4; ++gg) bia[gg] = bias[gg * 1024 + q * 16 + en];

    float c_state = 0.f;

    __shared__ float gtile[8][16][17];   // 8 wave D-tiles, 16x16 fp32, +1 pad

    unsigned int* gflags = flags + (size_t)g * 64 * FLAG_STRIDE_DW;
    unsigned int* myflag = gflags + (size_t)q * FLAG_STRIDE_DW;

    for (int t = 0; t < SEQ; ++t) {
        // ---- x part (no dependence on h_{t-1}) ----
        f32x4 acc0 = {0.f, 0.f, 0.f, 0.f};
        {
            const float* xrow = x + ((size_t)(batch0 + m16) * SEQ + t) * ISZ
                                  + kh * 256 + quad * 8;
            #pragma unroll
            for (int kk = 0; kk < 8; ++kk) {
                f32x4 x0 = *(const f32x4*)(xrow + kk * 32);
                f32x4 x1 = *(const f32x4*)(xrow + kk * 32 + 4);
                bf16x8 a;
                a[0] = f2bf(x0[0]); a[1] = f2bf(x0[1]);
                a[2] = f2bf(x0[2]); a[3] = f2bf(x0[3]);
                a[4] = f2bf(x1[0]); a[5] = f2bf(x1[1]);
                a[6] = f2bf(x1[2]); a[7] = f2bf(x1[3]);
                acc0 = __builtin_amdgcn_mfma_f32_16x16x32_bf16(a, wx[kk], acc0, 0, 0, 0);
            }
        }

        // ---- wait: all 64 CUs of this group published step t-1 ----
        // lane-parallel poll: lane j reads flag j (its own cacheline, single
        // writer -> no ping-pong, no RMW contention)
        if (tid < 64) {
            const unsigned int target = (unsigned int)t;
            long long guard = 0;
            for (;;) {
                unsigned int v = __hip_atomic_load(
                    gflags + (size_t)lane * FLAG_STRIDE_DW,
                    __ATOMIC_ACQUIRE, __HIP_MEMORY_SCOPE_AGENT);
                if (__all(v >= target)) break;
                __builtin_amdgcn_s_sleep(1);
                if (++guard > (1LL << 24)) break;   // anti-hang safety valve
            }
        }
        __syncthreads();

        // ---- h part: acc += h_{t-1} @ Wh, two parallel 8-chains ----
        f32x4 acc1 = {0.f, 0.f, 0.f, 0.f};
        {
            const int rb = (t + 1) & 1;   // buffer holding h_{t-1}
            const unsigned short* hrow = hex + ((size_t)rb * BATCH + batch0 + m16) * HSZ
                                             + kh * 512 + quad * 8;
            #pragma unroll
            for (int kk = 0; kk < 8; ++kk) {
                bf16x8 a0 = *(const bf16x8*)(hrow + kk * 32);
                bf16x8 a1 = *(const bf16x8*)(hrow + (kk + 8) * 32);
                acc0 = __builtin_amdgcn_mfma_f32_16x16x32_bf16(a0, wh[kk], acc0, 0, 0, 0);
                acc1 = __builtin_amdgcn_mfma_f32_16x16x32_bf16(a1, wh[kk + 8], acc1, 0, 0, 0);
            }
        }

        // ---- D tile -> LDS (C/D layout: col = lane&15, row = quad*4 + reg) ----
        #pragma unroll
        for (int r = 0; r < 4; ++r)
            gtile[w][quad * 4 + r][m16] = acc0[r] + acc1[r];
        __syncthreads();

        // ---- elementwise gate math (256 threads = 16 batches x 16 cols) ----
        float h_val = 0.f;
        if (tid < 256) {
            float gf = gtile[0][em][en] + gtile[4][em][en] + bia[0];
            float gi = gtile[1][em][en] + gtile[5][em][en] + bia[1];
            float gc = gtile[2][em][en] + gtile[6][em][en] + bia[2];
            float go = gtile[3][em][en] + gtile[7][em][en] + bia[3];
            float f  = sigm(gf);
            float i  = sigm(gi);
            float ct = tanh_fast(gc);
            float o  = sigm(go);
            c_state  = f * c_state + i * ct;
            h_val    = o * tanh_fast(c_state);

            // bf16 exchange write FIRST (critical path)
            const int wb = t & 1;
            hex[((size_t)wb * BATCH + batch0 + em) * HSZ + q * 16 + en] =
                (unsigned short)f2bf(h_val);
        }

        // ---- publish h_t ASAP ----
        __threadfence();
        __syncthreads();
        if (tid == 0) {
            __hip_atomic_store(myflag, (unsigned int)(t + 1),
                               __ATOMIC_RELEASE, __HIP_MEMORY_SCOPE_AGENT);
        }

        // ---- off-critical-path stores ----
        if (tid < 256) {
            out[((size_t)(batch0 + em) * SEQ + t) * HSZ + q * 16 + en] = h_val;
            if (t == SEQ - 1) {
                size_t fin = (size_t)BATCH * SEQ * HSZ;
                out[fin + (size_t)(batch0 + em) * HSZ + q * 16 + en] = h_val;
                out[fin + (size_t)BATCH * HSZ + (size_t)(batch0 + em) * HSZ
                        + q * 16 + en] = c_state;
            }
        }
    }
}

extern "C" void kernel_launch(void* const* d_in, const int* in_sizes, int n_in,
                              void* d_out, int out_size, void* d_ws, size_t ws_size,
                              hipStream_t stream) {
    const float* x    = (const float*)d_in[0];
    const float* W    = (const float*)d_in[1];
    const float* bias = (const float*)d_in[2];
    float* out        = (float*)d_out;

    unsigned short* hex   = (unsigned short*)d_ws;
    unsigned int*   flags = (unsigned int*)((char*)d_ws + HEX_BYTES);

    // zero h0 exchange buffers + arrival flags (ws re-poisoned 0xAA each launch)
    hipMemsetAsync(d_ws, 0, HEX_BYTES + FLAG_BYTES, stream);

    lstm_persistent<<<256, 512, 0, stream>>>(x, W, bias, out, hex, flags);
}

// Round 3
// 6551.071 us; speedup vs baseline: 3.8663x; 3.8663x over previous
//
#include <hip/hip_runtime.h>
#include <hip/hip_bf16.h>

// SimpleLSTM on MI355X — round 3: fence-free step synchronization.
//   B=64, S=512, I=512, H=1024, gates = 4H = 4096
// R2 post-mortem: barrier topology irrelevant (R1 24.1ms ~ R2 25.3ms). Common
// cost: per-step agent-scope acquire/release fences -> buffer_wbl2/buffer_inv
// (full L2 writeback/invalidate per block per step, serialized at TCC ~48us).
// R3 removes ALL fences:
//   * hex + flags accessed ONLY via agent-scope RELAXED atomics (per-access
//     coherent, sc0/sc1 -> device coherence point; no L2 walk)
//   * producer ordering: raw `s_waitcnt vmcnt(0)` in the storing wave between
//     h stores and flag store (coherent stores are visible once acked)
//   * consumer ordering: data dependence through the poll branch + coherent loads
//   * no __threadfence anywhere in the loop

#define BATCH 64
#define SEQ   512
#define ISZ   512
#define HSZ   1024
#define G4    4096

typedef short bf16x8 __attribute__((ext_vector_type(8)));
typedef float f32x4  __attribute__((ext_vector_type(4)));

#define HEX_BYTES (2 * BATCH * HSZ * 2)     // 2 buffers x [64][1024] bf16 = 256 KB
#define FLAG_STRIDE_DW 32                   // 128 B between flags
#define FLAG_BYTES (4 * 64 * FLAG_STRIDE_DW * 4)  // 4 groups x 64 flags = 32 KB

static __device__ __forceinline__ short f2bf(float f) {
    __hip_bfloat16 h = __float2bfloat16(f);
    return *reinterpret_cast<short*>(&h);
}
static __device__ __forceinline__ float sigm(float x) {
    return 1.f / (1.f + __expf(-x));
}
static __device__ __forceinline__ float tanh_fast(float x) {
    x = fminf(15.f, fmaxf(-15.f, x));
    float e = __expf(2.f * x);
    return (e - 1.f) / (e + 1.f);
}

__global__ __launch_bounds__(512) void lstm_persistent(
    const float* __restrict__ x,     // [B][S][I] fp32
    const float* __restrict__ W,     // [I+H][4H] fp32
    const float* __restrict__ bias,  // [4H] fp32
    float* __restrict__ out,         // [B][S][H] outputs, then [B][H] h, [B][H] c
    unsigned short* __restrict__ hex,// [2][B][H] bf16 exchange (coherent atomics only)
    unsigned int* __restrict__ flags)// [4][64] arrival epochs, 128 B stride
{
    const int tid  = threadIdx.x;
    const int bid  = blockIdx.x;
    const int q    = bid & 63;          // CU index within group (owns h cols q*16..+16)
    const int g    = bid >> 6;          // batch group 0..3
    const int w    = tid >> 6;          // wave 0..7
    const int lane = tid & 63;
    const int gb   = w & 3;             // gate block: 0=f 1=i 2=c~ 3=o
    const int kh   = w >> 2;            // K-half split across wave pairs
    const int m16  = lane & 15;
    const int quad = lane >> 4;
    const int batch0 = g * 16;
    const int colbase = gb * 1024 + q * 16;   // gate column base for this wave

    // ---- preload weights into registers as MFMA B-fragments ----
    // B-frag layout (16x16x32 bf16): lane holds B[k = quad*8 + j][n = lane&15]
    bf16x8 wh[16];   // Wh[kh*512 .. +512][colbase..+16], 16 K-chunks of 32
    bf16x8 wx[8];    // Wx[kh*256 .. +256][colbase..+16],  8 K-chunks of 32
    {
        const int n = m16;
        #pragma unroll
        for (int kk = 0; kk < 16; ++kk) {
            #pragma unroll
            for (int j = 0; j < 8; ++j) {
                int k = kh * 512 + kk * 32 + quad * 8 + j;
                wh[kk][j] = f2bf(W[(size_t)(ISZ + k) * G4 + colbase + n]);
            }
        }
        #pragma unroll
        for (int kk = 0; kk < 8; ++kk) {
            #pragma unroll
            for (int j = 0; j < 8; ++j) {
                int k = kh * 256 + kk * 32 + quad * 8 + j;
                wx[kk][j] = f2bf(W[(size_t)k * G4 + colbase + n]);
            }
        }
    }

    // elementwise mapping (tid < 256): m = tid>>4 (batch-in-group), n = tid&15 (col)
    const int em = tid >> 4;
    const int en = tid & 15;
    float bia[4];
    #pragma unroll
    for (int gg = 0; gg < 4; ++gg) bia[gg] = bias[gg * 1024 + q * 16 + en];

    float c_state = 0.f;

    __shared__ float gtile[8][16][20];   // 8 wave D-tiles (stride 20: 2-way max = free)
    __shared__ float htile[16][20];      // h staging for the packing wave

    unsigned int* gflags = flags + (size_t)g * 64 * FLAG_STRIDE_DW;
    unsigned int* myflag = gflags + (size_t)q * FLAG_STRIDE_DW;

    for (int t = 0; t < SEQ; ++t) {
        // ---- x part (no dependence on h_{t-1}; hides skew) ----
        f32x4 acc0 = {0.f, 0.f, 0.f, 0.f};
        {
            const float* xrow = x + ((size_t)(batch0 + m16) * SEQ + t) * ISZ
                                  + kh * 256 + quad * 8;
            #pragma unroll
            for (int kk = 0; kk < 8; ++kk) {
                f32x4 x0 = *(const f32x4*)(xrow + kk * 32);
                f32x4 x1 = *(const f32x4*)(xrow + kk * 32 + 4);
                bf16x8 a;
                a[0] = f2bf(x0[0]); a[1] = f2bf(x0[1]);
                a[2] = f2bf(x0[2]); a[3] = f2bf(x0[3]);
                a[4] = f2bf(x1[0]); a[5] = f2bf(x1[1]);
                a[6] = f2bf(x1[2]); a[7] = f2bf(x1[3]);
                acc0 = __builtin_amdgcn_mfma_f32_16x16x32_bf16(a, wx[kk], acc0, 0, 0, 0);
            }
        }

        // ---- wait: all 64 CUs of this group published step t-1 (RELAXED poll) ----
        if (tid < 64) {
            const unsigned int target = (unsigned int)t;
            long long guard = 0;
            for (;;) {
                unsigned int v = __hip_atomic_load(
                    gflags + (size_t)lane * FLAG_STRIDE_DW,
                    __ATOMIC_RELAXED, __HIP_MEMORY_SCOPE_AGENT);
                if (__all((int)(v >= target))) break;
                __builtin_amdgcn_s_sleep(1);
                if (++guard > (1LL << 24)) break;   // anti-hang safety valve
            }
        }
        __syncthreads();

        // ---- h part: acc += h_{t-1} @ Wh (coherent loads, two parallel chains) ----
        f32x4 acc1 = {0.f, 0.f, 0.f, 0.f};
        {
            const int rb = (t + 1) & 1;   // buffer holding h_{t-1}
            unsigned short* hrow = hex + ((size_t)rb * BATCH + batch0 + m16) * HSZ
                                       + kh * 512 + quad * 8;
            #pragma unroll
            for (int kk = 0; kk < 8; ++kk) {
                unsigned long long p0 = __hip_atomic_load(
                    (unsigned long long*)(hrow + kk * 32),
                    __ATOMIC_RELAXED, __HIP_MEMORY_SCOPE_AGENT);
                unsigned long long p1 = __hip_atomic_load(
                    (unsigned long long*)(hrow + kk * 32 + 4),
                    __ATOMIC_RELAXED, __HIP_MEMORY_SCOPE_AGENT);
                unsigned long long p2 = __hip_atomic_load(
                    (unsigned long long*)(hrow + (kk + 8) * 32),
                    __ATOMIC_RELAXED, __HIP_MEMORY_SCOPE_AGENT);
                unsigned long long p3 = __hip_atomic_load(
                    (unsigned long long*)(hrow + (kk + 8) * 32 + 4),
                    __ATOMIC_RELAXED, __HIP_MEMORY_SCOPE_AGENT);
                union { unsigned long long u[2]; bf16x8 v; } c0, c1;
                c0.u[0] = p0; c0.u[1] = p1;
                c1.u[0] = p2; c1.u[1] = p3;
                acc0 = __builtin_amdgcn_mfma_f32_16x16x32_bf16(c0.v, wh[kk], acc0, 0, 0, 0);
                acc1 = __builtin_amdgcn_mfma_f32_16x16x32_bf16(c1.v, wh[kk + 8], acc1, 0, 0, 0);
            }
        }

        // ---- D tile -> LDS (C/D layout: col = lane&15, row = quad*4 + reg) ----
        #pragma unroll
        for (int r = 0; r < 4; ++r)
            gtile[w][quad * 4 + r][m16] = acc0[r] + acc1[r];
        __syncthreads();

        // ---- elementwise gate math (256 threads = 16 batches x 16 cols) ----
        float h_val = 0.f;
        if (tid < 256) {
            float gf = gtile[0][em][en] + gtile[4][em][en] + bia[0];
            float gi = gtile[1][em][en] + gtile[5][em][en] + bia[1];
            float gc = gtile[2][em][en] + gtile[6][em][en] + bia[2];
            float go = gtile[3][em][en] + gtile[7][em][en] + bia[3];
            float f  = sigm(gf);
            float i  = sigm(gi);
            float ct = tanh_fast(gc);
            float o  = sigm(go);
            c_state  = f * c_state + i * ct;
            h_val    = o * tanh_fast(c_state);
            htile[em][en] = h_val;
        }
        __syncthreads();

        // ---- pack + coherent publish (wave 0 only; no fences) ----
        if (tid < 64) {
            const int b  = tid >> 2;
            const int j4 = (tid & 3) * 4;
            unsigned short us[4];
            us[0] = (unsigned short)f2bf(htile[b][j4 + 0]);
            us[1] = (unsigned short)f2bf(htile[b][j4 + 1]);
            us[2] = (unsigned short)f2bf(htile[b][j4 + 2]);
            us[3] = (unsigned short)f2bf(htile[b][j4 + 3]);
            unsigned long long pk;
            __builtin_memcpy(&pk, us, 8);
            const int wb = t & 1;
            __hip_atomic_store(
                (unsigned long long*)(hex + ((size_t)wb * BATCH + batch0 + b) * HSZ
                                          + q * 16 + j4),
                pk, __ATOMIC_RELAXED, __HIP_MEMORY_SCOPE_AGENT);
            // drain the coherent h stores (this wave issued all of them),
            // then publish the flag — no wbl2, no inv.
            __asm__ volatile("s_waitcnt vmcnt(0)" ::: "memory");
            if (tid == 0) {
                __hip_atomic_store(myflag, (unsigned int)(t + 1),
                                   __ATOMIC_RELAXED, __HIP_MEMORY_SCOPE_AGENT);
            }
        }

        // ---- off-critical-path stores ----
        if (tid < 256) {
            out[((size_t)(batch0 + em) * SEQ + t) * HSZ + q * 16 + en] = h_val;
            if (t == SEQ - 1) {
                size_t fin = (size_t)BATCH * SEQ * HSZ;
                out[fin + (size_t)(batch0 + em) * HSZ + q * 16 + en] = h_val;
                out[fin + (size_t)BATCH * HSZ + (size_t)(batch0 + em) * HSZ
                        + q * 16 + en] = c_state;
            }
        }
    }
}

extern "C" void kernel_launch(void* const* d_in, const int* in_sizes, int n_in,
                              void* d_out, int out_size, void* d_ws, size_t ws_size,
                              hipStream_t stream) {
    const float* x    = (const float*)d_in[0];
    const float* W    = (const float*)d_in[1];
    const float* bias = (const float*)d_in[2];
    float* out        = (float*)d_out;

    unsigned short* hex   = (unsigned short*)d_ws;
    unsigned int*   flags = (unsigned int*)((char*)d_ws + HEX_BYTES);

    // zero h0 exchange buffers + arrival flags (ws re-poisoned 0xAA each launch;
    // dispatch boundary makes this visible to the coherent accesses in-kernel)
    hipMemsetAsync(d_ws, 0, HEX_BYTES + FLAG_BYTES, stream);

    lstm_persistent<<<256, 512, 0, stream>>>(x, W, bias, out, hex, flags);
}